// Round 11
// baseline (171.635 us; speedup 1.0000x reference)
//
#include <hip/hip_runtime.h>

#define IN_CH 128
#define OUT_CH 64
#define NEG_SLOPE 0.2f

#define BSHIFT 10       // 1024 nodes per partition
#define CEDGE 1024      // edges per bin chunk
#define CAPMAX 36864    // records per partition (mean 32.7K + ~22 sigma)
#define OVFL_CAP 65536  // overflow list entries (statistically never used)
#define CBUF 8192       // compacted-record LDS buffer (32 KB)
// p0 accumulated as 22-bit fixed point; u64 = (cnt<<32) | sum(fx22).
#define FIX22 4194304.0f

typedef short bf16x8 __attribute__((ext_vector_type(8)));
typedef float f32x4 __attribute__((ext_vector_type(4)));
typedef unsigned int u32x4 __attribute__((ext_vector_type(4)));
typedef unsigned long long u64;
typedef unsigned int u32;

__device__ __forceinline__ unsigned short f2bf(float f) {
  union { float f; unsigned u; } v;
  v.f = f;
  unsigned r = v.u + 0x7FFF + ((v.u >> 16) & 1);  // RNE
  return (unsigned short)(r >> 16);
}

__device__ __forceinline__ float bf2f(unsigned short h) {
  union { unsigned u; float f; } v;
  v.u = (unsigned)h << 16;
  return v.f;
}

struct NodeSh {
  float sxi0[64], sxi1[64], sxj0[64], sxj1[64];      // xh-part scores
  float sei0[64], sei1[64], sej0[64], sej1[64];      // emb-part scores
};
struct BinSh {
  u32 recs[CEDGE];    // 4 KB
  int hist4[4][64];   // per-wave histograms
  int cur4[4][64];    // per-wave cursors
  int scn[64], gbase[64];
};

// ---------------------------------------------------------------------------
// Kernel 0 (prep): 64 blocks. Builds the transposed global bf16 B^T table
// lwt[c][k] = bf16(lw[k][c]) (32 KB, L1-resident for the gemm loads) and
// zeroes the gcur cursors. REPLACES the former hipMemsetAsync — same
// dispatch count, removes the 32 KB LDS B-table from node_bin (which was
// capping both fused roles at 4 blocks/CU and starving node's registers).
// ---------------------------------------------------------------------------
__global__ __launch_bounds__(256) void prep_kernel(
    const float* __restrict__ lw, unsigned short* __restrict__ lwt,
    int* __restrict__ gcur) {
  const int bid = blockIdx.x;
  const int tid = threadIdx.x;
  if (bid == 0 && tid < 72) gcur[tid] = 0;
  int idx = bid * 256 + tid;  // 0..16383
  int k = idx >> 7;
  int c = idx & 127;
  lwt[(size_t)c * IN_CH + k] = f2bf(lw[idx]);
}

// ---------------------------------------------------------------------------
// Kernel 1 (node ∥ bin role-fused). Round-11 change: node role reads B^T
// from the global lwt table (round-0 proven, L1-resident) instead of an LDS
// B-table. Union LDS drops 34 KB -> ~6.5 KB: bin role regains 8 blocks/CU,
// node role sheds the LDS-staging register pressure that was spilling at
// the allocator's 64-VGPR target. Roles interleaved by bid%3.
// ---------------------------------------------------------------------------
__global__ __launch_bounds__(256) void node_bin_kernel(
    const float* __restrict__ x, const float* __restrict__ emb,
    const unsigned short* __restrict__ lwt, const float* __restrict__ att_i,
    const float* __restrict__ att_j, const float* __restrict__ aei,
    const float* __restrict__ aej, const int* __restrict__ esrc,
    const int* __restrict__ edst, unsigned short* __restrict__ xhb,
    float2* __restrict__ si, float2* __restrict__ sj,
    float* __restrict__ wself, u32* __restrict__ brecs,
    int* __restrict__ gcur, u64* __restrict__ ovfl, int cap, int nnode,
    int nchunk, int N, int E) {
  __shared__ union { NodeSh n; BinSh b; } sh;
  const int bid = blockIdx.x;
  const int tid = threadIdx.x;
  const int wave = tid >> 6;
  const int lane = tid & 63;

  const bool isNode = ((bid % 3) == 0) && (bid / 3 < nnode);
  if (isNode) {
    // ========================= node role =========================
    const int n0 = (bid / 3) * 64;

    // ---- emb dot pass: 4 threads per node, 16 channels each ----
    {
      int ln = tid >> 2;
      int q = tid & 3;
      int n = n0 + ln;
      float ei0 = 0.f, ei1 = 0.f, ej0 = 0.f, ej1 = 0.f;
      if (n < N) {
        const float* ep = emb + (size_t)n * OUT_CH + q * 16;
#pragma unroll
        for (int j4 = 0; j4 < 4; ++j4) {
          float4 e4 = *(const float4*)(ep + j4 * 4);
          float vals[4] = {e4.x, e4.y, e4.z, e4.w};
#pragma unroll
          for (int j = 0; j < 4; ++j) {
            int d = q * 16 + j4 * 4 + j;
            ei0 = fmaf(vals[j], aei[d], ei0);
            ei1 = fmaf(vals[j], aei[64 + d], ei1);
            ej0 = fmaf(vals[j], aej[d], ej0);
            ej1 = fmaf(vals[j], aej[64 + d], ej1);
          }
        }
      }
#pragma unroll
      for (int off = 1; off < 4; off <<= 1) {
        ei0 += __shfl_xor(ei0, off, 64);
        ei1 += __shfl_xor(ei1, off, 64);
        ej0 += __shfl_xor(ej0, off, 64);
        ej1 += __shfl_xor(ej1, off, 64);
      }
      if (q == 0) {
        sh.n.sei0[ln] = ei0; sh.n.sei1[ln] = ei1;
        sh.n.sej0[ln] = ej0; sh.n.sej1[ln] = ej1;
      }
    }

    // ---- MFMA tile (B^T from global lwt, L1-resident) + score partials ----
    const int ccol = lane & 15;
    const int rg = lane >> 4;
    const int ko = rg * 8;
    const int row0 = n0 + wave * 16;
    int arow = row0 + ccol;
    if (arow >= N) arow = N - 1;
    const float* ap = x + (size_t)arow * IN_CH + ko;
    bf16x8 a[4];
#pragma unroll
    for (int kb = 0; kb < 4; ++kb) {
      float4 f0 = *(const float4*)(ap + kb * 32);
      float4 f1 = *(const float4*)(ap + kb * 32 + 4);
      bf16x8 t;
      t[0] = (short)f2bf(f0.x); t[1] = (short)f2bf(f0.y);
      t[2] = (short)f2bf(f0.z); t[3] = (short)f2bf(f0.w);
      t[4] = (short)f2bf(f1.x); t[5] = (short)f2bf(f1.y);
      t[6] = (short)f2bf(f1.z); t[7] = (short)f2bf(f1.w);
      a[kb] = t;
    }

    const int crow0 = row0 + rg * 4;
    float pI0[4] = {0,0,0,0}, pI1[4] = {0,0,0,0};
    float pJ0[4] = {0,0,0,0}, pJ1[4] = {0,0,0,0};
#pragma unroll
    for (int nt = 0; nt < 8; ++nt) {
      f32x4 acc = {0.f, 0.f, 0.f, 0.f};
      const bf16x8* bp =
          (const bf16x8*)(lwt + (size_t)(nt * 16 + ccol) * IN_CH + ko);
      acc = __builtin_amdgcn_mfma_f32_16x16x32_bf16(a[0], bp[0], acc, 0, 0, 0);
      acc = __builtin_amdgcn_mfma_f32_16x16x32_bf16(a[1], bp[4], acc, 0, 0, 0);
      acc = __builtin_amdgcn_mfma_f32_16x16x32_bf16(a[2], bp[8], acc, 0, 0, 0);
      acc = __builtin_amdgcn_mfma_f32_16x16x32_bf16(a[3], bp[12], acc, 0, 0, 0);
      float ai = att_i[nt * 16 + ccol];
      float aj = att_j[nt * 16 + ccol];
#pragma unroll
      for (int rr = 0; rr < 4; ++rr) {
        int n = crow0 + rr;
        if (n < N) xhb[(size_t)n * IN_CH + nt * 16 + ccol] = f2bf(acc[rr]);
        if (nt < 4) {
          pI0[rr] = fmaf(acc[rr], ai, pI0[rr]);
          pJ0[rr] = fmaf(acc[rr], aj, pJ0[rr]);
        } else {
          pI1[rr] = fmaf(acc[rr], ai, pI1[rr]);
          pJ1[rr] = fmaf(acc[rr], aj, pJ1[rr]);
        }
      }
    }
#pragma unroll
    for (int off = 1; off < 16; off <<= 1) {
#pragma unroll
      for (int rr = 0; rr < 4; ++rr) {
        pI0[rr] += __shfl_xor(pI0[rr], off, 64);
        pI1[rr] += __shfl_xor(pI1[rr], off, 64);
        pJ0[rr] += __shfl_xor(pJ0[rr], off, 64);
        pJ1[rr] += __shfl_xor(pJ1[rr], off, 64);
      }
    }
    if (ccol == 0) {
#pragma unroll
      for (int rr = 0; rr < 4; ++rr) {
        int ln = wave * 16 + rg * 4 + rr;
        sh.n.sxi0[ln] = pI0[rr]; sh.n.sxi1[ln] = pI1[rr];
        sh.n.sxj0[ln] = pJ0[rr]; sh.n.sxj1[ln] = pJ1[rr];
      }
    }
    __syncthreads();

    if (tid < 64) {
      int n = n0 + tid;
      if (n < N) {
        float vi0 = sh.n.sxi0[tid] + sh.n.sei0[tid];
        float vi1 = sh.n.sxi1[tid] + sh.n.sei1[tid];
        float vj0 = sh.n.sxj0[tid] + sh.n.sej0[tid];
        float vj1 = sh.n.sxj1[tid] + sh.n.sej1[tid];
        si[n] = make_float2(vi0, vi1);
        sj[n] = make_float2(vj0, vj1);
        float a0 = vi0 + vj0;
        float a1 = vi1 + vj1;
        a0 = a0 > 0.f ? a0 : NEG_SLOPE * a0;
        a1 = a1 > 0.f ? a1 : NEG_SLOPE * a1;
        wself[n] = 1.f / (1.f + __expf(a1 - a0));
      }
    }
  } else {
    // ========================= bin role (sort-only) =========================
    const int c = (bid < 3 * nnode) ? (bid - bid / 3 - 1) : (bid - nnode);
    if (c >= nchunk) return;
    const long e0 = (long)c * CEDGE;
    const int cnt = (int)min((long)CEDGE, (long)E - e0);

    sh.b.hist4[wave][tid & 63] = 0;  // wave-private: in-wave ordering suffices

    int dv[4], sv[4];
#pragma unroll
    for (int k = 0; k < 4; ++k) {
      int r = (k << 8) + tid;
      dv[k] = (r < cnt) ? edst[e0 + r] : -1;
      sv[k] = (r < cnt) ? esrc[e0 + r] : 0;
    }
#pragma unroll
    for (int k = 0; k < 4; ++k)
      if (dv[k] >= 0) atomicAdd(&sh.b.hist4[wave][dv[k] >> BSHIFT], 1);
    __syncthreads();

    // wave-0: sum per-wave hists, shuffle scan, gcur atomic, cursor bases
    if (tid < 64) {
      int h0 = sh.b.hist4[0][tid], h1 = sh.b.hist4[1][tid];
      int h2 = sh.b.hist4[2][tid], h3 = sh.b.hist4[3][tid];
      int h = h0 + h1 + h2 + h3;
      int v = h;
#pragma unroll
      for (int off = 1; off < 64; off <<= 1) {
        int t = __shfl_up(v, off, 64);
        if (tid >= off) v += t;
      }
      int excl = v - h;
      sh.b.scn[tid] = excl;
      sh.b.gbase[tid] = (h > 0) ? atomicAdd(&gcur[tid], h) : 0;
      sh.b.cur4[0][tid] = excl;
      sh.b.cur4[1][tid] = excl + h0;
      sh.b.cur4[2][tid] = excl + h0 + h1;
      sh.b.cur4[3][tid] = excl + h0 + h1 + h2;
    }
    __syncthreads();

    // scatter sort-only records: (dlocal10 << 17) | src17
#pragma unroll
    for (int k = 0; k < 4; ++k) {
      if (dv[k] >= 0) {
        int pos = atomicAdd(&sh.b.cur4[wave][dv[k] >> BSHIFT], 1);
        sh.b.recs[pos] = ((u32)(dv[k] & 1023) << 17) | (u32)sv[k];
      }
    }
    __syncthreads();

    // coalesced writeout; partition via 6-iter binary search over scn
#pragma unroll
    for (int k = 0; k < 4; ++k) {
      int p = (k << 8) + tid;
      if (p < cnt) {
        int lo = 0, hi = 63;
#pragma unroll
        for (int it = 0; it < 6; ++it) {
          int mid = (lo + hi + 1) >> 1;
          if (sh.b.scn[mid] <= p) lo = mid; else hi = mid - 1;
        }
        int b = lo;
        int gofs = sh.b.gbase[b] + (p - sh.b.scn[b]);
        u32 rec = sh.b.recs[p];
        if (gofs < cap) {
          brecs[(size_t)b * cap + gofs] = rec;
        } else {  // ~never (cap = mean + 22 sigma): overflow list
          int idx = atomicAdd(&gcur[64], 1);
          if (idx < OVFL_CAP) ovfl[idx] = ((u64)b << 32) | (u64)rec;
        }
      }
    }
  }
}

// ---------------------------------------------------------------------------
// Kernel 2 (reduce + score + out) — verbatim from round 10 (verified).
// Phase 1: u32x4 vector scan + wave-ballot compact (dense, no divergent
// gathers). Phase 2: dense drain — si gather, sigmoid, LDS u64 accumulate.
// XCD-affine (p,q) mapping kept.
// ---------------------------------------------------------------------------
__global__ __launch_bounds__(256) void reduce_out_kernel(
    const unsigned short* __restrict__ xhb, const float2* __restrict__ si,
    const float2* __restrict__ sjg, const float* __restrict__ wself,
    const u32* __restrict__ brecs, const int* __restrict__ gcur,
    const u64* __restrict__ ovfl, int cap, float* __restrict__ out, int N,
    int nbkt) {
  __shared__ u64 tab[64];
  __shared__ float2 sjl[64];
  __shared__ u32 cbuf[CBUF];  // 32 KB
  __shared__ int cused;
  const int bid = blockIdx.x;
  const int xcd = bid & 7;        // XCD under round-robin dispatch
  const int t = bid >> 3;
  const int pg = t >> 4;          // partition group
  const int q = t & 15;           // 64-node sub-bucket
  const int p = xcd + (pg << 3);  // all q-blocks of p share this XCD
  if (p >= nbkt) return;
  const int n0 = (p << BSHIFT) + (q << 6);
  if (n0 >= N) return;
  const int tid = threadIdx.x;
  const int lane = tid & 63;
  const u64 lmlt = ((u64)1 << lane) - 1;  // lanemask_lt

  if (tid == 0) cused = 0;
  if (tid < 64) {
    tab[tid] = 0ull;
    int nn = n0 + tid;
    sjl[tid] = (nn < N) ? sjg[nn] : make_float2(0.f, 0.f);
  }
  __syncthreads();

  const int cnt = min(gcur[p], cap);
  const u32* rp = brecs + (size_t)p * cap;
  const u64 one = (1ull << 32);

#define APPEND(rec, valid)                                              \
  do {                                                                  \
    u32 _r = (rec);                                                     \
    bool _mt = (valid) && ((int)((_r >> 23) & 15) == q);                \
    u64 _m = __ballot(_mt);                                             \
    int _nb = __popcll(_m);                                             \
    int _wb = 0;                                                        \
    if (lane == 0 && _nb) _wb = atomicAdd(&cused, _nb);                 \
    _wb = __shfl(_wb, 0, 64);                                           \
    if (_mt) cbuf[_wb + __popcll(_m & lmlt)] = _r;                      \
  } while (0)

#define DRAIN()                                                         \
  do {                                                                  \
    int _used = cused;                                                  \
    if (_used > CBUF) _used = CBUF;                                     \
    for (int _r = tid; _r < _used; _r += 256) {                         \
      u32 _rc = cbuf[_r];                                               \
      float2 aa = si[_rc & 0x1FFFF];                                    \
      int _ln = (int)((_rc >> 17) & 63);                                \
      float2 bb = sjl[_ln];                                             \
      float a0 = aa.x + bb.x;                                           \
      float a1 = aa.y + bb.y;                                           \
      a0 = a0 > 0.f ? a0 : NEG_SLOPE * a0;                              \
      a1 = a1 > 0.f ? a1 : NEG_SLOPE * a1;                              \
      float p0 = 1.f / (1.f + __expf(a1 - a0));                         \
      u32 fx = (u32)fminf(p0 * FIX22 + 0.5f, 4194303.0f);               \
      atomicAdd(&tab[_ln], one | (u64)fx);                              \
    }                                                                   \
    __syncthreads();                                                    \
    if (tid == 0) cused = 0;                                            \
    __syncthreads();                                                    \
  } while (0)

  // phase 1: vector scan + compact (2048 records per sweep)
  int base = 0;
  for (; base + 2048 <= cnt; base += 2048) {
    u32x4 va = *(const u32x4*)(rp + base + tid * 4);
    u32x4 vb = *(const u32x4*)(rp + base + 1024 + tid * 4);
#pragma unroll
    for (int j = 0; j < 4; ++j) APPEND(va[j], true);
#pragma unroll
    for (int j = 0; j < 4; ++j) APPEND(vb[j], true);
    __syncthreads();  // cused visible
    if (cused > CBUF - 2048) DRAIN();
  }
  // tail sweep (scalar, uniform loop bound)
  for (int r0 = base; r0 < cnt; r0 += 256) {
    int r = r0 + tid;
    u32 rec = (r < cnt) ? rp[r] : 0u;
    APPEND(rec, r < cnt);
  }
  // overflow list (statistically empty) — direct divergent path is fine
  const int oc = min(gcur[64], OVFL_CAP);
  for (int r = tid; r < oc; r += 256) {
    u64 e = ovfl[r];
    u32 rc = (u32)e;
    if ((int)(e >> 32) == p && (int)((rc >> 23) & 15) == q) {
      float2 aa = si[rc & 0x1FFFF];
      int ln = (int)((rc >> 17) & 63);
      float2 bb = sjl[ln];
      float a0 = aa.x + bb.x;
      float a1 = aa.y + bb.y;
      a0 = a0 > 0.f ? a0 : NEG_SLOPE * a0;
      a1 = a1 > 0.f ? a1 : NEG_SLOPE * a1;
      float p0 = 1.f / (1.f + __expf(a1 - a0));
      u32 fx = (u32)fminf(p0 * FIX22 + 0.5f, 4194303.0f);
      atomicAdd(&tab[ln], one | (u64)fx);
    }
  }
  __syncthreads();
  DRAIN();  // final dense drain
#undef APPEND
#undef DRAIN

  const int nmax = min(64, N - n0);
  for (int it = tid; it < nmax * 16; it += 256) {
    int ln = it >> 4;
    int n = n0 + ln;
    int c4 = (it & 15) << 2;
    u64 acc = tab[ln];
    float cnt_f = (float)(u32)(acc >> 32);
    float s0 = (float)(u32)(acc & 0xFFFFFFFFu) * (1.0f / FIX22);
    float ps = wself[n];
    float w0 = 0.5f * (s0 + ps);
    float w1 = 0.5f * ((cnt_f - s0) + (1.f - ps));
    ushort4 h0 = *(const ushort4*)&xhb[(size_t)n * IN_CH + c4];
    ushort4 h1 = *(const ushort4*)&xhb[(size_t)n * IN_CH + 64 + c4];
    float4 o;
    o.x = fmaf(bf2f(h0.x), w0, bf2f(h1.x) * w1);
    o.y = fmaf(bf2f(h0.y), w0, bf2f(h1.y) * w1);
    o.z = fmaf(bf2f(h0.z), w0, bf2f(h1.z) * w1);
    o.w = fmaf(bf2f(h0.w), w0, bf2f(h1.w) * w1);
    *(float4*)&out[(size_t)n * OUT_CH + c4] = o;
  }
}

extern "C" void kernel_launch(void* const* d_in, const int* in_sizes, int n_in,
                              void* d_out, int out_size, void* d_ws,
                              size_t ws_size, hipStream_t stream) {
  const float* x = (const float*)d_in[0];
  const float* emb = (const float*)d_in[1];
  const float* lw = (const float*)d_in[2];
  const float* att_i = (const float*)d_in[3];
  const float* att_j = (const float*)d_in[4];
  const float* aei = (const float*)d_in[5];
  const float* aej = (const float*)d_in[6];
  const int* esrc = (const int*)d_in[7];
  const int* edst = (const int*)d_in[8];
  float* out = (float*)d_out;

  int N = in_sizes[0] / IN_CH;  // 50000
  int E = in_sizes[7];          // 1600000
  int nbkt = (N + 1023) >> BSHIFT;       // 49 dst partitions
  int nchunk = (E + CEDGE - 1) / CEDGE;  // 1563 bin chunks
  int nnode = (N + 63) / 64;             // 782 node tiles
  int ngrp = (nbkt + 7) >> 3;
  int nred = 8 * ngrp * 16;              // 896 reduce blocks (XCD-affine)

  char* ws = (char*)d_ws;
  float2* si = (float2*)ws;                           // N float2
  float2* sj = si + N;                                // N float2
  float* wself = (float*)(sj + N);                    // N f32
  unsigned short* xhb = (unsigned short*)(wself + N); // N*128 bf16 (12.8 MB)
  int* gcur = (int*)(xhb + (size_t)N * IN_CH);        // 80 ints (72 + pad)
  unsigned short* lwt = (unsigned short*)(gcur + 80); // 16384 bf16 (32 KB)
  u64* ovfl = (u64*)(lwt + 16384);                    // OVFL_CAP u64 (512 KB)
  u32* brecs = (u32*)(ovfl + OVFL_CAP);               // nbkt * cap records

  size_t fixed = (size_t)((char*)brecs - ws);
  size_t avail = ws_size > fixed ? (ws_size - fixed) / 4 : 0;
  int cap = (int)(avail / (nbkt > 0 ? nbkt : 1));
  if (cap > CAPMAX) cap = CAPMAX;
  if (cap < 4096) cap = 4096;  // overflow list keeps this correct anyway
  cap &= ~3;                   // 16B-aligned record regions for u32x4 loads

  int grid1 = nnode + nchunk;
  if (grid1 < 3 * nnode - 2) grid1 = 3 * nnode - 2;  // role-interleave cover

  prep_kernel<<<dim3(64), dim3(256), 0, stream>>>(lw, lwt, gcur);
  node_bin_kernel<<<dim3(grid1), dim3(256), 0, stream>>>(
      x, emb, lwt, att_i, att_j, aei, aej, esrc, edst, xhb, si, sj, wself,
      brecs, gcur, ovfl, cap, nnode, nchunk, N, E);
  reduce_out_kernel<<<dim3(nred), dim3(256), 0, stream>>>(
      xhb, si, sj, wself, brecs, gcur, ovfl, cap, out, N, nbkt);
}

// Round 12
// 155.851 us; speedup vs baseline: 1.1013x; 1.1013x over previous
//
#include <hip/hip_runtime.h>

#define IN_CH 128
#define OUT_CH 64
#define NEG_SLOPE 0.2f

#define BSHIFT 10       // 1024 nodes per partition
#define CEDGE 2048      // edges per bin block (8 units of 256)
#define CAPMAX 36864    // records per partition (mean 32.7K + ~22 sigma)
// p0 stored as 22-bit fixed point; u64 accumulate = (cnt<<32) | sum(fx22).
#define FIX22 4194304.0f

typedef short bf16x8 __attribute__((ext_vector_type(8)));
typedef float f32x4 __attribute__((ext_vector_type(4)));
typedef unsigned int u32x4 __attribute__((ext_vector_type(4)));
typedef unsigned long long u64;
typedef unsigned int u32;

__device__ __forceinline__ unsigned short f2bf(float f) {
  union { float f; unsigned u; } v;
  v.f = f;
  unsigned r = v.u + 0x7FFF + ((v.u >> 16) & 1);  // RNE
  return (unsigned short)(r >> 16);
}

__device__ __forceinline__ float bf2f(unsigned short h) {
  union { unsigned u; float f; } v;
  v.u = (unsigned)h << 16;
  return v.f;
}

// ---------------------------------------------------------------------------
// Kernel 1 (node): 782 blocks x 256. Per block (64 nodes):
//  - build bf16 B-table in LDS from lw (L2-resident).
//  - MFMA 64x128x128 tile: xh = x @ lw, x read ONCE.
//  - scores from the f32 accumulators + emb dot pass.
//  - writes xhb(bf16), si/sj, wself, seeds wsum64=0. Block 0 zeroes gcur.
// (verbatim round 8 — verified in the 159.8 us best run; fusing this with
//  bin was tried 3x (r9-r11): allocator compromises at 64 VGPR and spills.)
// ---------------------------------------------------------------------------
__global__ __launch_bounds__(256) void node_kernel(
    const float* __restrict__ x, const float* __restrict__ emb,
    const float* __restrict__ lw, const float* __restrict__ att_i,
    const float* __restrict__ att_j, const float* __restrict__ aei,
    const float* __restrict__ aej, unsigned short* __restrict__ xhb,
    float2* __restrict__ si, float2* __restrict__ sj,
    float* __restrict__ wself, u64* __restrict__ wsum64,
    int* __restrict__ gcur, int N) {
  __shared__ unsigned short blds[16384];  // 32 KB B-table
  __shared__ float sxi0[64], sxi1[64], sxj0[64], sxj1[64];  // xh-part scores
  __shared__ float sei0[64], sei1[64], sej0[64], sej1[64];  // emb-part scores

  const int bid = blockIdx.x;
  const int tid = threadIdx.x;
  const int wave = tid >> 6;
  const int lane = tid & 63;
  const int n0 = bid * 64;

  if (bid == 0 && tid < 64) gcur[tid] = 0;

  // ---- emb dot pass: 4 threads per node, 16 channels each ----
  {
    int ln = tid >> 2;
    int q = tid & 3;
    int n = n0 + ln;
    float ei0 = 0.f, ei1 = 0.f, ej0 = 0.f, ej1 = 0.f;
    if (n < N) {
      const float* ep = emb + (size_t)n * OUT_CH + q * 16;
#pragma unroll
      for (int j4 = 0; j4 < 4; ++j4) {
        float4 e4 = *(const float4*)(ep + j4 * 4);
        float vals[4] = {e4.x, e4.y, e4.z, e4.w};
#pragma unroll
        for (int j = 0; j < 4; ++j) {
          int d = q * 16 + j4 * 4 + j;
          ei0 = fmaf(vals[j], aei[d], ei0);
          ei1 = fmaf(vals[j], aei[64 + d], ei1);
          ej0 = fmaf(vals[j], aej[d], ej0);
          ej1 = fmaf(vals[j], aej[64 + d], ej1);
        }
      }
    }
#pragma unroll
    for (int off = 1; off < 4; off <<= 1) {
      ei0 += __shfl_xor(ei0, off, 64);
      ei1 += __shfl_xor(ei1, off, 64);
      ej0 += __shfl_xor(ej0, off, 64);
      ej1 += __shfl_xor(ej1, off, 64);
    }
    if (q == 0) { sei0[ln] = ei0; sei1[ln] = ei1; sej0[ln] = ej0; sej1[ln] = ej1; }
  }

  // ---- build B-table in LDS (coalesced lw reads, conflict-free writes) ----
  {
    int col = tid & 127;
    int kc2 = tid >> 7;  // 0/1: low/high half of kc range
#pragma unroll
    for (int i = 0; i < 8; ++i) {
      int kc = kc2 * 8 + i;
      bf16x8 t;
#pragma unroll
      for (int j = 0; j < 8; ++j)
        t[j] = (short)f2bf(lw[(size_t)(kc * 8 + j) * IN_CH + col]);
      *(bf16x8*)&blds[(kc * 128 + col) * 8] = t;
    }
  }
  __syncthreads();

  // ---- MFMA tile + score partials from f32 accumulators ----
  const int ccol = lane & 15;
  const int rg = lane >> 4;  // row group 0..3
  const int ko = rg * 8;
  const int row0 = n0 + wave * 16;
  int arow = row0 + ccol;
  if (arow >= N) arow = N - 1;  // clamped read; stores guarded
  const float* ap = x + (size_t)arow * IN_CH + ko;
  bf16x8 a[4];
#pragma unroll
  for (int kb = 0; kb < 4; ++kb) {
    float4 f0 = *(const float4*)(ap + kb * 32);
    float4 f1 = *(const float4*)(ap + kb * 32 + 4);
    bf16x8 t;
    t[0] = (short)f2bf(f0.x); t[1] = (short)f2bf(f0.y);
    t[2] = (short)f2bf(f0.z); t[3] = (short)f2bf(f0.w);
    t[4] = (short)f2bf(f1.x); t[5] = (short)f2bf(f1.y);
    t[6] = (short)f2bf(f1.z); t[7] = (short)f2bf(f1.w);
    a[kb] = t;
  }

  const int crow0 = row0 + rg * 4;
  const bf16x8* bls = (const bf16x8*)blds;
  float pI0[4] = {0,0,0,0}, pI1[4] = {0,0,0,0};
  float pJ0[4] = {0,0,0,0}, pJ1[4] = {0,0,0,0};
#pragma unroll
  for (int nt = 0; nt < 8; ++nt) {
    f32x4 acc = {0.f, 0.f, 0.f, 0.f};
#pragma unroll
    for (int kb = 0; kb < 4; ++kb)
      acc = __builtin_amdgcn_mfma_f32_16x16x32_bf16(
          a[kb], bls[(kb * 4 + rg) * 128 + nt * 16 + ccol], acc, 0, 0, 0);
    float ai = att_i[nt * 16 + ccol];
    float aj = att_j[nt * 16 + ccol];
#pragma unroll
    for (int rr = 0; rr < 4; ++rr) {
      int n = crow0 + rr;
      if (n < N) xhb[(size_t)n * IN_CH + nt * 16 + ccol] = f2bf(acc[rr]);
      if (nt < 4) {
        pI0[rr] = fmaf(acc[rr], ai, pI0[rr]);
        pJ0[rr] = fmaf(acc[rr], aj, pJ0[rr]);
      } else {
        pI1[rr] = fmaf(acc[rr], ai, pI1[rr]);
        pJ1[rr] = fmaf(acc[rr], aj, pJ1[rr]);
      }
    }
  }
  // reduce over the 16 columns held by this row group
#pragma unroll
  for (int off = 1; off < 16; off <<= 1) {
#pragma unroll
    for (int rr = 0; rr < 4; ++rr) {
      pI0[rr] += __shfl_xor(pI0[rr], off, 64);
      pI1[rr] += __shfl_xor(pI1[rr], off, 64);
      pJ0[rr] += __shfl_xor(pJ0[rr], off, 64);
      pJ1[rr] += __shfl_xor(pJ1[rr], off, 64);
    }
  }
  if (ccol == 0) {
#pragma unroll
    for (int rr = 0; rr < 4; ++rr) {
      int ln = wave * 16 + rg * 4 + rr;
      sxi0[ln] = pI0[rr]; sxi1[ln] = pI1[rr];
      sxj0[ln] = pJ0[rr]; sxj1[ln] = pJ1[rr];
    }
  }
  __syncthreads();

  // ---- combine + write per-node outputs ----
  if (tid < 64) {
    int n = n0 + tid;
    if (n < N) {
      float vi0 = sxi0[tid] + sei0[tid];
      float vi1 = sxi1[tid] + sei1[tid];
      float vj0 = sxj0[tid] + sej0[tid];
      float vj1 = sxj1[tid] + sej1[tid];
      si[n] = make_float2(vi0, vi1);
      sj[n] = make_float2(vj0, vj1);
      float a0 = vi0 + vj0;
      float a1 = vi1 + vj1;
      a0 = a0 > 0.f ? a0 : NEG_SLOPE * a0;
      a1 = a1 > 0.f ? a1 : NEG_SLOPE * a1;
      wself[n] = 1.f / (1.f + __expf(a1 - a0));
      wsum64[n] = 0ull;  // spill-fallback baseline
    }
  }
}

// ---------------------------------------------------------------------------
// Kernel 2 (bin): round-12 change vs round 8: CEDGE 1024 -> 2048, 8-deep
// per-thread batches. All blocks are co-resident either way (782 @ ~10 KB
// LDS), so wall time ≈ one block's barrier-separated critical path; 8-deep
// halves the per-edge barrier/scan/search overhead while the extra loads
// issue in parallel within each phase. Early si/sj gathers + per-wave
// hist/cursor replicas kept (round-7 wins).
// ---------------------------------------------------------------------------
__global__ __launch_bounds__(256) void bin_kernel(
    const int* __restrict__ esrc, const int* __restrict__ edst,
    const float2* __restrict__ si, const float2* __restrict__ sj,
    u32* __restrict__ brecs, int* __restrict__ gcur,
    u64* __restrict__ wsum64, int cap, int E) {
  __shared__ u32 recs[CEDGE];       // 8 KB
  __shared__ int hist4[4][64];      // per-wave histograms
  __shared__ int cur4[4][64];       // per-wave cursors (pre-based)
  __shared__ int scn[64], gbase[64];
  const int bid = blockIdx.x;
  const int tid = threadIdx.x;
  const int wave = tid >> 6;

  const long e0 = (long)bid * CEDGE;
  const int cnt = (int)min((long)CEDGE, (long)E - e0);

  hist4[tid >> 6][tid & 63] = 0;  // 256 slots, one per thread

  // edge-index loads + si/sj gathers issued EARLY (arrive during hist/scan)
  int dv[8];
  float2 av[8], bv[8];
#pragma unroll
  for (int k = 0; k < 8; ++k) {
    int r = (k << 8) + tid;
    dv[k] = (r < cnt) ? edst[e0 + r] : -1;
  }
#pragma unroll
  for (int k = 0; k < 8; ++k) {
    if (dv[k] >= 0) {
      int r = (k << 8) + tid;
      av[k] = si[esrc[e0 + r]];
      bv[k] = sj[dv[k]];
    }
  }
  __syncthreads();  // hist4 zeroed

#pragma unroll
  for (int k = 0; k < 8; ++k)
    if (dv[k] >= 0) atomicAdd(&hist4[wave][dv[k] >> BSHIFT], 1);
  __syncthreads();

  // wave-0: sum per-wave hists, shuffle prefix scan, per-wave cursor bases
  if (tid < 64) {
    int h0 = hist4[0][tid], h1 = hist4[1][tid];
    int h2 = hist4[2][tid], h3 = hist4[3][tid];
    int h = h0 + h1 + h2 + h3;
    int v = h;
#pragma unroll
    for (int off = 1; off < 64; off <<= 1) {
      int t = __shfl_up(v, off, 64);
      if (tid >= off) v += t;
    }
    int excl = v - h;
    scn[tid] = excl;
    gbase[tid] = (h > 0) ? atomicAdd(&gcur[tid], h) : 0;
    cur4[0][tid] = excl;
    cur4[1][tid] = excl + h0;
    cur4[2][tid] = excl + h0 + h1;
    cur4[3][tid] = excl + h0 + h1 + h2;
  }
  __syncthreads();

  // score + LDS scatter (gather data long since arrived)
#pragma unroll
  for (int k = 0; k < 8; ++k) {
    if (dv[k] >= 0) {
      float a0 = av[k].x + bv[k].x;
      float a1 = av[k].y + bv[k].y;
      a0 = a0 > 0.f ? a0 : NEG_SLOPE * a0;
      a1 = a1 > 0.f ? a1 : NEG_SLOPE * a1;
      float p0 = 1.f / (1.f + __expf(a1 - a0));
      u32 fx = (u32)fminf(p0 * FIX22 + 0.5f, 4194303.0f);  // 22-bit
      int pos = atomicAdd(&cur4[wave][dv[k] >> BSHIFT], 1);
      recs[pos] = ((u32)(dv[k] & 1023) << 22) | fx;
    }
  }
  __syncthreads();

  // coalesced writeout; partition via 6-iter binary search over scn
#pragma unroll
  for (int k = 0; k < 8; ++k) {
    int p = (k << 8) + tid;
    if (p < cnt) {
      int lo = 0, hi = 63;
#pragma unroll
      for (int it = 0; it < 6; ++it) {
        int mid = (lo + hi + 1) >> 1;
        if (scn[mid] <= p) lo = mid; else hi = mid - 1;
      }
      int b = lo;
      int gofs = gbase[b] + (p - scn[b]);
      u32 rec = recs[p];
      if (gofs < cap) {
        brecs[(size_t)b * cap + gofs] = rec;
      } else {  // rare spill: packed u64 device atomic
        atomicAdd(&wsum64[(b << BSHIFT) + (int)(rec >> 22)],
                  (1ull << 32) | (u64)(rec & 0x3FFFFFu));
      }
    }
  }
}

// ---------------------------------------------------------------------------
// Kernel 3 (reduce + out): verbatim round 8 (verified in the 159.8 us run).
// XCD-affine (p,q) mapping + u32x4 vector scan, 2 loads in flight per
// iteration; predicated LDS u64 atomic (no gathers/exp here — cheap).
// ---------------------------------------------------------------------------
__global__ __launch_bounds__(256) void reduce_out_kernel(
    const unsigned short* __restrict__ xhb, const u64* __restrict__ wsum64,
    const float* __restrict__ wself, const u32* __restrict__ brecs,
    const int* __restrict__ gcur, int cap, float* __restrict__ out, int N,
    int nbkt) {
  __shared__ u64 tab[64];
  const int bid = blockIdx.x;
  const int xcd = bid & 7;        // XCD under round-robin dispatch
  const int t = bid >> 3;
  const int pg = t >> 4;          // partition group
  const int q = t & 15;           // 64-node sub-bucket
  const int p = xcd + (pg << 3);  // all q-blocks of p share this XCD
  if (p >= nbkt) return;
  const int n0 = (p << BSHIFT) + (q << 6);
  if (n0 >= N) return;
  const int tid = threadIdx.x;

  if (tid < 64) tab[tid] = 0ull;
  __syncthreads();

  const int cnt = min(gcur[p], cap);
  const u32* rp = brecs + (size_t)p * cap;
  const u64 one = (1ull << 32);

  // main scan: 2048 records per block-iteration (2x dwordx4 per thread)
  int base = 0;
  for (; base + 2048 <= cnt; base += 2048) {
    u32x4 va = *(const u32x4*)(rp + base + tid * 4);
    u32x4 vb = *(const u32x4*)(rp + base + 1024 + tid * 4);
#pragma unroll
    for (int j = 0; j < 4; ++j) {
      u32 rec = va[j];
      if ((int)(rec >> 28) == q)
        atomicAdd(&tab[(rec >> 22) & 63], one | (u64)(rec & 0x3FFFFFu));
    }
#pragma unroll
    for (int j = 0; j < 4; ++j) {
      u32 rec = vb[j];
      if ((int)(rec >> 28) == q)
        atomicAdd(&tab[(rec >> 22) & 63], one | (u64)(rec & 0x3FFFFFu));
    }
  }
  // tail (< 2048 records), scalar
  for (int r = base + tid; r < cnt; r += 256) {
    u32 rec = rp[r];
    if ((int)(rec >> 28) == q)
      atomicAdd(&tab[(rec >> 22) & 63], one | (u64)(rec & 0x3FFFFFu));
  }
  __syncthreads();

  const int nmax = min(64, N - n0);
  for (int it = tid; it < nmax * 16; it += 256) {
    int ln = it >> 4;
    int n = n0 + ln;
    int c4 = (it & 15) << 2;
    u64 acc = tab[ln] + wsum64[n];  // spill baseline shares packing
    float cnt_f = (float)(u32)(acc >> 32);
    float s0 = (float)(u32)(acc & 0xFFFFFFFFu) * (1.0f / FIX22);
    float ps = wself[n];
    float w0 = 0.5f * (s0 + ps);
    float w1 = 0.5f * ((cnt_f - s0) + (1.f - ps));
    ushort4 h0 = *(const ushort4*)&xhb[(size_t)n * IN_CH + c4];
    ushort4 h1 = *(const ushort4*)&xhb[(size_t)n * IN_CH + 64 + c4];
    float4 o;
    o.x = fmaf(bf2f(h0.x), w0, bf2f(h1.x) * w1);
    o.y = fmaf(bf2f(h0.y), w0, bf2f(h1.y) * w1);
    o.z = fmaf(bf2f(h0.z), w0, bf2f(h1.z) * w1);
    o.w = fmaf(bf2f(h0.w), w0, bf2f(h1.w) * w1);
    *(float4*)&out[(size_t)n * OUT_CH + c4] = o;
  }
}

extern "C" void kernel_launch(void* const* d_in, const int* in_sizes, int n_in,
                              void* d_out, int out_size, void* d_ws,
                              size_t ws_size, hipStream_t stream) {
  const float* x = (const float*)d_in[0];
  const float* emb = (const float*)d_in[1];
  const float* lw = (const float*)d_in[2];
  const float* att_i = (const float*)d_in[3];
  const float* att_j = (const float*)d_in[4];
  const float* aei = (const float*)d_in[5];
  const float* aej = (const float*)d_in[6];
  const int* esrc = (const int*)d_in[7];
  const int* edst = (const int*)d_in[8];
  float* out = (float*)d_out;

  int N = in_sizes[0] / IN_CH;  // 50000
  int E = in_sizes[7];          // 1600000
  int nbkt = (N + 1023) >> BSHIFT;       // 49 dst partitions
  int nchunk = (E + CEDGE - 1) / CEDGE;  // 782 bin blocks
  int ntile = (N + 63) / 64;             // 782 node blocks
  int ngrp = (nbkt + 7) >> 3;            // 7 partition groups per XCD
  int nred = 8 * ngrp * 16;              // 896 reduce blocks (XCD-affine)

  char* ws = (char*)d_ws;
  u64* wsum64 = (u64*)ws;                            // N u64
  float2* si = (float2*)(wsum64 + N);                // N float2
  float2* sj = si + N;                               // N float2
  float* wself = (float*)(sj + N);                   // N f32
  unsigned short* xhb = (unsigned short*)(wself + N);  // N*128 bf16 (12.8 MB)
  int* gcur = (int*)(xhb + (size_t)N * IN_CH);       // 64 ints
  u32* brecs = (u32*)(gcur + 64);                    // nbkt * cap records

  size_t fixed = (size_t)((char*)brecs - ws);
  size_t avail = ws_size > fixed ? (ws_size - fixed) / 4 : 0;
  int cap = (int)(avail / (nbkt > 0 ? nbkt : 1));
  if (cap > CAPMAX) cap = CAPMAX;
  if (cap < 4096) cap = 4096;  // spill fallback keeps this correct anyway
  cap &= ~3;                   // 16B-aligned record regions for u32x4 loads

  node_kernel<<<dim3(ntile), dim3(256), 0, stream>>>(
      x, emb, lw, att_i, att_j, aei, aej, xhb, si, sj, wself, wsum64, gcur, N);
  bin_kernel<<<dim3(nchunk), dim3(256), 0, stream>>>(esrc, edst, si, sj, brecs,
                                                     gcur, wsum64, cap, E);
  reduce_out_kernel<<<dim3(nred), dim3(256), 0, stream>>>(
      xhb, wsum64, wself, brecs, gcur, cap, out, N, nbkt);
}